// Round 4
// baseline (52.947 us; speedup 1.0000x reference)
//
#include <hip/hip_runtime.h>
#include <hip/hip_bf16.h>

// Problem constants
#define M_ROWS   1792                 // 7 * 256 softpool rows
#define KDIM     512
#define OUT_FEAT_SZ (M_ROWS*1024)     // 1835008
#define OUT_HAT_SZ  (M_ROWS*512)      // 917504

typedef __attribute__((ext_vector_type(8))) __bf16 bf16x8;
typedef __attribute__((ext_vector_type(4))) float  f32x4;

__device__ __forceinline__ unsigned short f2bf(float f) {
    union { float f; unsigned int u; } v; v.f = f;
    unsigned int r = v.u + 0x7fffu + ((v.u >> 16) & 1u);   // RNE
    return (unsigned short)(r >> 16);
}

// f32 -> bf16 weight conversion (262144 elems each; blockIdx.y picks tensor)
__global__ __launch_bounds__(256) void cvt_k(
    const float* __restrict__ a, const float* __restrict__ b,
    unsigned short* __restrict__ oa, unsigned short* __restrict__ ob)
{
    const float* s = blockIdx.y ? b : a;
    unsigned short* d = blockIdx.y ? ob : oa;
    int i = blockIdx.x * 256 + threadIdx.x;   // 65536 threads, 4 elems each
    float4 v = reinterpret_cast<const float4*>(s)[i];
    ushort4 o; o.x=f2bf(v.x); o.y=f2bf(v.y); o.z=f2bf(v.z); o.w=f2bf(v.w);
    reinterpret_cast<ushort4*>(d)[i] = o;
}

// Fused softpool3d + fc2 + residual + softmax + concat.
// 8-row tiles, 448 blocks, 512 threads (8 waves), VGPR cap 128 for deep
// load pipelining (round-3 was latency-bound at VGPR=36).
//   softpool: thread owns 1 d'-pair x 4 rows (32 independent float4 loads)
//   GEMM:     wave w owns cols [w*64, w*64+64); A rows 8-15 dup'd via arow&7
//   softmax:  wave w owns row w (8 rows / 8 waves)
__global__ __launch_bounds__(512, 4) void fused_k(
    const float* __restrict__ x, const float* __restrict__ y,
    const unsigned short* __restrict__ wv_bf, const unsigned short* __restrict__ wt_bf,
    const float* __restrict__ b_v, const float* __restrict__ b_t,
    const float* __restrict__ wvec, float* __restrict__ d_out)
{
    const int side = blockIdx.y;
    const float* in          = side ? y     : x;
    const unsigned short* B  = side ? wt_bf : wv_bf;
    const float* bias        = side ? b_t   : b_v;
    const int mbase = blockIdx.x * 8;
    const int bp = mbase >> 8;       // b' (constant in tile; 8 divides 256)
    const int l0 = mbase & 255;      // l' base

    __shared__ unsigned short tA[8 * 520];   // bf16 softpool tile (A), padded
    __shared__ float resl[8 * 516];          // f32 softpool/residual -> logits

    const int tid = threadIdx.x;
    const int u  = tid & 255;        // d'-pair (d' = 2u, 2u+1)
    const int rh = tid >> 8;         // 0..1 row half

    // ---- softpool: 4 rows per thread, 32 independent loads for pipelining
    #pragma unroll
    for (int ri = 0; ri < 4; ++ri) {
        int r = rh * 4 + ri;
        const float* base = in + ((size_t)(2*bp) * 512 + 2*(l0 + r)) * 1024 + 4*u;
        float4 v[8];
        #pragma unroll
        for (int i = 0; i < 4; ++i)
            #pragma unroll
            for (int j = 0; j < 2; ++j)
                v[i*2+j] = *reinterpret_cast<const float4*>(base + ((size_t)(i*512 + j))*1024);
        float num0=0.f, den0=0.f, num1=0.f, den1=0.f;
        #pragma unroll
        for (int k = 0; k < 8; ++k) {
            float e0=__expf(v[k].x), e1=__expf(v[k].y), e2=__expf(v[k].z), e3=__expf(v[k].w);
            num0 += e0*v[k].x + e1*v[k].y;  den0 += e0 + e1;
            num1 += e2*v[k].z + e3*v[k].w;  den1 += e2 + e3;
        }
        float s0 = num0/den0, s1 = num1/den1;
        *reinterpret_cast<float2*>(&resl[r*516 + 2*u]) = make_float2(s0, s1);
        unsigned int pk = (unsigned int)f2bf(s0) | ((unsigned int)f2bf(s1) << 16);
        *reinterpret_cast<unsigned int*>(&tA[r*520 + 2*u]) = pk;
    }
    __syncthreads();

    // ---- GEMM: 8 waves, wave w -> cols [w*64, w*64+64)
    const int lane = tid & 63;
    const int w    = tid >> 6;       // 0..7
    const int arow = lane & 15;
    const int kq   = lane >> 4;      // 0..3
    const int nb   = w * 64;

    f32x4 acc[4];
    #pragma unroll
    for (int t = 0; t < 4; ++t) acc[t] = (f32x4){0.f,0.f,0.f,0.f};

    #pragma unroll 4
    for (int ks = 0; ks < 16; ++ks) {
        int kk = ks*32 + kq*8;
        bf16x8 af = *reinterpret_cast<const bf16x8*>(&tA[(arow & 7)*520 + kk]);
        #pragma unroll
        for (int t = 0; t < 4; ++t) {
            bf16x8 bf = *reinterpret_cast<const bf16x8*>(B + (size_t)(nb + t*16 + arow) * KDIM + kk);
            acc[t] = __builtin_amdgcn_mfma_f32_16x16x32_bf16(af, bf, acc[t], 0, 0, 0);
        }
    }

    // ---- epilogue: logits = acc + bias (+ residual side 0); rows 0..7 only
    if (kq < 2) {
        #pragma unroll
        for (int t = 0; t < 4; ++t) {
            int n = nb + t*16 + arow;
            float bn = bias[n];
            #pragma unroll
            for (int i = 0; i < 4; ++i) {
                int row = kq*4 + i;    // C/D: col=lane&15, row=(lane>>4)*4+i
                float v = acc[t][i] + bn;
                if (side == 0) v += resl[row*516 + n];
                resl[row*516 + n] = v;
            }
        }
    }
    __syncthreads();

    // ---- softmax: wave w handles row w (full 512 cols, 8 per lane)
    float ew0 = __expf(wvec[0]), ew1 = __expf(wvec[1]);
    float wsc = (side ? ew1 : ew0) / (ew0 + ew1);
    float* feat = d_out;
    float* hat  = d_out + OUT_FEAT_SZ + (size_t)side * OUT_HAT_SZ;

    {
        int m = mbase + w;
        const float* lp = &resl[w*516 + lane*8];
        float4 v0 = *reinterpret_cast<const float4*>(lp);
        float4 v1 = *reinterpret_cast<const float4*>(lp + 4);
        float mx = fmaxf(fmaxf(fmaxf(v0.x,v0.y), fmaxf(v0.z,v0.w)),
                         fmaxf(fmaxf(v1.x,v1.y), fmaxf(v1.z,v1.w)));
        #pragma unroll
        for (int s = 32; s; s >>= 1) mx = fmaxf(mx, __shfl_xor(mx, s));
        float e0=__expf(v0.x-mx), e1=__expf(v0.y-mx), e2=__expf(v0.z-mx), e3=__expf(v0.w-mx);
        float e4=__expf(v1.x-mx), e5=__expf(v1.y-mx), e6=__expf(v1.z-mx), e7=__expf(v1.w-mx);
        float sum = ((e0+e1)+(e2+e3)) + ((e4+e5)+(e6+e7));
        #pragma unroll
        for (int s = 32; s; s >>= 1) sum += __shfl_xor(sum, s);
        float inv = 1.f / sum;
        float4 p0 = {e0*inv, e1*inv, e2*inv, e3*inv};
        float4 p1 = {e4*inv, e5*inv, e6*inv, e7*inv};
        *reinterpret_cast<float4*>(&hat[(size_t)m*512 + lane*8])     = p0;
        *reinterpret_cast<float4*>(&hat[(size_t)m*512 + lane*8 + 4]) = p1;
        float4 f0 = {p0.x*wsc, p0.y*wsc, p0.z*wsc, p0.w*wsc};
        float4 f1 = {p1.x*wsc, p1.y*wsc, p1.z*wsc, p1.w*wsc};
        size_t fo = (size_t)m*1024 + side*512 + lane*8;
        *reinterpret_cast<float4*>(&feat[fo])     = f0;
        *reinterpret_cast<float4*>(&feat[fo + 4]) = f1;
    }
}

extern "C" void kernel_launch(void* const* d_in, const int* in_sizes, int n_in,
                              void* d_out, int out_size, void* d_ws, size_t ws_size,
                              hipStream_t stream)
{
    const float* x        = (const float*)d_in[0];
    const float* y        = (const float*)d_in[1];
    const float* w_fc2_t  = (const float*)d_in[12];
    const float* b_fc2_t  = (const float*)d_in[13];
    const float* w_fc2_v  = (const float*)d_in[14];
    const float* b_fc2_v  = (const float*)d_in[15];
    const float* wvec     = (const float*)d_in[18];

    unsigned short* wv_bf = (unsigned short*)d_ws;   // 262144 bf16
    unsigned short* wt_bf = wv_bf + 262144;          // 262144 bf16

    // 1) weights -> bf16
    cvt_k<<<dim3(256, 2), 256, 0, stream>>>(w_fc2_v, w_fc2_t, wv_bf, wt_bf);
    // 2) fused softpool + fc2 + residual + softmax + concat (8-row tiles)
    fused_k<<<dim3(M_ROWS/8, 2), 512, 0, stream>>>(
        x, y, wv_bf, wt_bf, b_fc2_v, b_fc2_t, wvec, (float*)d_out);
}

// Round 5
// 38.379 us; speedup vs baseline: 1.3796x; 1.3796x over previous
//
#include <hip/hip_runtime.h>
#include <hip/hip_bf16.h>

// Problem constants
#define M_ROWS   1792                 // 7 * 256 softpool rows
#define KDIM     512
#define OUT_FEAT_SZ (M_ROWS*1024)     // 1835008
#define OUT_HAT_SZ  (M_ROWS*512)      // 917504

typedef __attribute__((ext_vector_type(8))) __bf16 bf16x8;
typedef __attribute__((ext_vector_type(4))) float  f32x4;
typedef __attribute__((ext_vector_type(8))) unsigned short ushort8v;

__device__ __forceinline__ unsigned short f2bf(float f) {
    union { float f; unsigned int u; } v; v.f = f;
    unsigned int r = v.u + 0x7fffu + ((v.u >> 16) & 1u);   // RNE
    return (unsigned short)(r >> 16);
}

// K1: softpool3d (4,2,2)/(2,2,2) rows (blocks 0..1791) + weight f32->bf16
// cvt (blocks 1792..1919). blockIdx.y = tensor side.
// Softpool: 1 output row per block; thread u owns d' pair (2u,2u+1); the 8
// float4 taps are issued as one clustered burst (sched_group_barrier) so each
// wave keeps 8 loads in flight (round-4 was latency-bound at 1-2 in flight).
__global__ __launch_bounds__(256) void sp_k(
    const float* __restrict__ x, const float* __restrict__ y,
    const float* __restrict__ wv, const float* __restrict__ wt,
    float* __restrict__ xsp, float* __restrict__ ysp,
    unsigned short* __restrict__ wvb, unsigned short* __restrict__ wtb)
{
    const int side = blockIdx.y;
    if (blockIdx.x >= M_ROWS) {
        // ---- weight cvt: 128 blocks x 256 thr x 8 elems = 262144
        int blk = blockIdx.x - M_ROWS;
        const float* s = side ? wt : wv;
        unsigned short* d = side ? wtb : wvb;
        int i = (blk * 256 + threadIdx.x) * 8;
        float4 v0 = *reinterpret_cast<const float4*>(s + i);
        float4 v1 = *reinterpret_cast<const float4*>(s + i + 4);
        ushort8v o;
        o[0]=f2bf(v0.x); o[1]=f2bf(v0.y); o[2]=f2bf(v0.z); o[3]=f2bf(v0.w);
        o[4]=f2bf(v1.x); o[5]=f2bf(v1.y); o[6]=f2bf(v1.z); o[7]=f2bf(v1.w);
        *reinterpret_cast<ushort8v*>(d + i) = o;
        return;
    }
    const float* in  = side ? y   : x;
    float*       out = side ? ysp : xsp;
    const int r  = blockIdx.x;
    const int bp = r >> 8;        // b' 0..6
    const int lp = r & 255;       // l'
    const int u  = threadIdx.x;   // d' pair

    const float* base = in + ((size_t)(2*bp) * 512 + 2*lp) * 1024 + 4*u;
    float4 v[8];
    #pragma unroll
    for (int i = 0; i < 4; ++i)
        #pragma unroll
        for (int j = 0; j < 2; ++j)
            v[i*2+j] = *reinterpret_cast<const float4*>(base + ((size_t)(i*512 + j))*1024);
    // pin: all 8 VMEM reads scheduled before the compute burst
    __builtin_amdgcn_sched_group_barrier(0x20, 8, 0);

    float num0=0.f, den0=0.f, num1=0.f, den1=0.f;
    #pragma unroll
    for (int k = 0; k < 8; ++k) {
        float e0=__expf(v[k].x), e1=__expf(v[k].y), e2=__expf(v[k].z), e3=__expf(v[k].w);
        num0 += e0*v[k].x + e1*v[k].y;  den0 += e0 + e1;
        num1 += e2*v[k].z + e3*v[k].w;  den1 += e2 + e3;
    }
    *reinterpret_cast<float2*>(out + (size_t)r*512 + 2*u) =
        make_float2(num0/den0, num1/den1);
}

// K3: C = A @ W^T + bias (+ residual A, side 0), row-softmax N=512, write hat
// + scaled feature half. 16-row tiles (224 blocks: minimal B re-read, B lives
// in L2), 1024 thr / 16 waves; wave w owns cols [w*32,w*32+32); B register-
// double-buffered 2 ks ahead so the MFMA chain hides L2 latency.
__global__ __launch_bounds__(1024) void gemm_sm_k(
    const float* __restrict__ xsp, const float* __restrict__ ysp,
    const unsigned short* __restrict__ wvb, const unsigned short* __restrict__ wtb,
    const float* __restrict__ bv, const float* __restrict__ bt,
    const float* __restrict__ wvec, float* __restrict__ d_out)
{
    const int side = blockIdx.y;
    const float* A           = side ? ysp : xsp;
    const unsigned short* B  = side ? wtb : wvb;
    const float* bias        = side ? bt  : bv;
    const int mbase = blockIdx.x * 16;

    __shared__ unsigned short tA[16 * 520];  // bf16 A tile, padded
    __shared__ float resl[16 * 516];         // f32 A copy (residual) -> logits

    const int tid = threadIdx.x;

    // ---- stage A: 16x512 f32 -> {bf16 tA, f32 resl}
    {
        const float* Ab = A + (size_t)mbase * KDIM;
        #pragma unroll
        for (int rr = 0; rr < 2; ++rr) {
            int f4  = tid + rr*1024;           // 0..2047
            float4 v = reinterpret_cast<const float4*>(Ab)[f4];
            int row = f4 >> 7;
            int col = (f4 & 127) << 2;
            ushort4 o; o.x=f2bf(v.x); o.y=f2bf(v.y); o.z=f2bf(v.z); o.w=f2bf(v.w);
            *reinterpret_cast<ushort4*>(&tA[row*520 + col]) = o;
            *reinterpret_cast<float4*>(&resl[row*516 + col]) = v;
        }
    }
    __syncthreads();

    const int lane = tid & 63;
    const int w    = tid >> 6;       // 0..15
    const int arow = lane & 15;
    const int kq   = lane >> 4;      // 0..3
    const int nb   = w * 32;

    f32x4 acc0 = (f32x4){0.f,0.f,0.f,0.f};
    f32x4 acc1 = (f32x4){0.f,0.f,0.f,0.f};

    const unsigned short* B0 = B + (size_t)(nb      + arow) * KDIM + kq*8;
    const unsigned short* B1 = B + (size_t)(nb + 16 + arow) * KDIM + kq*8;
    bf16x8 b0a = *reinterpret_cast<const bf16x8*>(B0);
    bf16x8 b1a = *reinterpret_cast<const bf16x8*>(B1);
    bf16x8 b0b = *reinterpret_cast<const bf16x8*>(B0 + 32);
    bf16x8 b1b = *reinterpret_cast<const bf16x8*>(B1 + 32);

    #pragma unroll
    for (int ks = 0; ks < 16; ++ks) {
        bf16x8 af = *reinterpret_cast<const bf16x8*>(&tA[arow*520 + ks*32 + kq*8]);
        bf16x8 c0 = b0a, c1 = b1a;
        b0a = b0b; b1a = b1b;
        if (ks < 14) {
            b0b = *reinterpret_cast<const bf16x8*>(B0 + (ks+2)*32);
            b1b = *reinterpret_cast<const bf16x8*>(B1 + (ks+2)*32);
        }
        acc0 = __builtin_amdgcn_mfma_f32_16x16x32_bf16(af, c0, acc0, 0, 0, 0);
        acc1 = __builtin_amdgcn_mfma_f32_16x16x32_bf16(af, c1, acc1, 0, 0, 0);
    }

    // ---- epilogue: logits = acc + bias (+ residual side 0), in-place
    #pragma unroll
    for (int t = 0; t < 2; ++t) {
        int n = nb + t*16 + arow;
        float bn = bias[n];
        f32x4 a = t ? acc1 : acc0;
        #pragma unroll
        for (int i = 0; i < 4; ++i) {
            int row = kq*4 + i;    // C/D: col=lane&15, row=(lane>>4)*4+i
            float vv = a[i] + bn;
            if (side == 0) vv += resl[row*516 + n];
            resl[row*516 + n] = vv;
        }
    }
    __syncthreads();

    // ---- softmax: wave w handles row w (full 512 cols, 8 per lane)
    float ew0 = __expf(wvec[0]), ew1 = __expf(wvec[1]);
    float wsc = (side ? ew1 : ew0) / (ew0 + ew1);
    float* feat = d_out;
    float* hat  = d_out + OUT_FEAT_SZ + (size_t)side * OUT_HAT_SZ;

    {
        int m = mbase + w;
        const float* lp = &resl[w*516 + lane*8];
        float4 v0 = *reinterpret_cast<const float4*>(lp);
        float4 v1 = *reinterpret_cast<const float4*>(lp + 4);
        float mx = fmaxf(fmaxf(fmaxf(v0.x,v0.y), fmaxf(v0.z,v0.w)),
                         fmaxf(fmaxf(v1.x,v1.y), fmaxf(v1.z,v1.w)));
        #pragma unroll
        for (int s = 32; s; s >>= 1) mx = fmaxf(mx, __shfl_xor(mx, s));
        float e0=__expf(v0.x-mx), e1=__expf(v0.y-mx), e2=__expf(v0.z-mx), e3=__expf(v0.w-mx);
        float e4=__expf(v1.x-mx), e5=__expf(v1.y-mx), e6=__expf(v1.z-mx), e7=__expf(v1.w-mx);
        float sum = ((e0+e1)+(e2+e3)) + ((e4+e5)+(e6+e7));
        #pragma unroll
        for (int s = 32; s; s >>= 1) sum += __shfl_xor(sum, s);
        float inv = 1.f / sum;
        float4 p0 = {e0*inv, e1*inv, e2*inv, e3*inv};
        float4 p1 = {e4*inv, e5*inv, e6*inv, e7*inv};
        *reinterpret_cast<float4*>(&hat[(size_t)m*512 + lane*8])     = p0;
        *reinterpret_cast<float4*>(&hat[(size_t)m*512 + lane*8 + 4]) = p1;
        float4 f0 = {p0.x*wsc, p0.y*wsc, p0.z*wsc, p0.w*wsc};
        float4 f1 = {p1.x*wsc, p1.y*wsc, p1.z*wsc, p1.w*wsc};
        size_t fo = (size_t)m*1024 + side*512 + lane*8;
        *reinterpret_cast<float4*>(&feat[fo])     = f0;
        *reinterpret_cast<float4*>(&feat[fo + 4]) = f1;
    }
}

extern "C" void kernel_launch(void* const* d_in, const int* in_sizes, int n_in,
                              void* d_out, int out_size, void* d_ws, size_t ws_size,
                              hipStream_t stream)
{
    const float* x        = (const float*)d_in[0];
    const float* y        = (const float*)d_in[1];
    const float* w_fc2_t  = (const float*)d_in[12];
    const float* b_fc2_t  = (const float*)d_in[13];
    const float* w_fc2_v  = (const float*)d_in[14];
    const float* b_fc2_v  = (const float*)d_in[15];
    const float* wvec     = (const float*)d_in[18];

    float* xsp = (float*)d_ws;                       // 917504 f32
    float* ysp = xsp + 917504;                       // 917504 f32
    unsigned short* wvb = (unsigned short*)(ysp + 917504);  // 262144 bf16
    unsigned short* wtb = wvb + 262144;              // 262144 bf16

    // 1) softpool (3584 row-blocks) + weight cvt (256 blocks), one launch
    sp_k<<<dim3(M_ROWS + 128, 2), 256, 0, stream>>>(
        x, y, w_fc2_v, w_fc2_t, xsp, ysp, wvb, wtb);
    // 2) fused fc2 + residual + softmax + concat
    gemm_sm_k<<<dim3(M_ROWS/16, 2), 1024, 0, stream>>>(
        xsp, ysp, wvb, wtb, b_fc2_v, b_fc2_t, wvec, (float*)d_out);
}